// Round 5
// baseline (216.425 us; speedup 1.0000x reference)
//
#include <hip/hip_runtime.h>

#define BB 8
#define NN 4096
#define MMK 1024
#define SMAX 8.0f

typedef __bf16 v8bf __attribute__((ext_vector_type(8)));
typedef float v4f __attribute__((ext_vector_type(4)));
typedef float v16f __attribute__((ext_vector_type(16)));
#define MFMA16 __builtin_amdgcn_mfma_f32_16x16x32_bf16
#define MFMA32 __builtin_amdgcn_mfma_f32_32x32x16_bf16

static __device__ __forceinline__ unsigned pkbf(float a, float b) {
    union { __bf16 h[2]; unsigned u; } o;
    o.h[0] = (__bf16)a; o.h[1] = (__bf16)b;
    return o.u;
}

// ---------------- Kernel 1: projections via MFMA, OUTPUT IN FRAG ORDER -------
// 64-token tiles: Q blocks 0..511, K 512..639, V 640..767 (3 blocks/CU).
// Frag layouts (16B chunk per lane), tok/qt/kt within batch:
//  Qfr chunk = ((b*128 + qt)*8 + s)*64 + lane : Q[q=qt*32+r31][c=s*16+h*8+j]
//  Kfr chunk = ((b*32  + kt)*8 + s)*64 + lane : K[key=kt*32+r31][c=s*16+h*8+j]
//  Vfr chunk = (((b*32 + kt)*4 + cg)*2 + t)*64 + lane : Vt[ch=cg*32+r31][key=kt*32+t*16+h*8+j]
#define XTS 68
__global__ __launch_bounds__(256, 1) void proj(
    const float* __restrict__ x, const float* __restrict__ y,
    const float* __restrict__ Wq, const float* __restrict__ bq,
    const float* __restrict__ Wk, const float* __restrict__ bk,
    const float* __restrict__ Wv, const float* __restrict__ bv,
    __bf16* __restrict__ Qfr, __bf16* __restrict__ Kfr, __bf16* __restrict__ Vfr)
{
    __shared__ __align__(16) __bf16 xt[128 * XTS];
    __shared__ float bsh[128];

    const int tid = threadIdx.x;
    const int wave = tid >> 6, lane = tid & 63, l15 = lane & 15, quad = lane >> 4;
    const int bid = blockIdx.x;

    int job, b, t0, stride;
    const float *in, *W, *bias;
    if (bid < 512)      { job = 0; b = bid >> 6;         t0 = (bid & 63) * 64;         in = x; stride = NN;  W = Wq; bias = bq; }
    else if (bid < 640) { job = 1; b = (bid - 512) >> 4; t0 = ((bid - 512) & 15) * 64; in = y; stride = MMK; W = Wk; bias = bk; }
    else                { job = 2; b = (bid - 640) >> 4; t0 = ((bid - 640) & 15) * 64; in = y; stride = MMK; W = Wv; bias = bv; }

    // stage [128 c][64 tok] fp32 -> bf16 LDS
    #pragma unroll
    for (int i = 0; i < 8; ++i) {
        const int s = i * 256 + tid;
        const int c = s >> 4, c4 = s & 15;
        float4 v = *(const float4*)(in + (size_t)(b * 128 + c) * stride + t0 + c4 * 4);
        union { __bf16 h[4]; uint2 u; } o;
        o.h[0] = (__bf16)v.x; o.h[1] = (__bf16)v.y; o.h[2] = (__bf16)v.z; o.h[3] = (__bf16)v.w;
        *(uint2*)(xt + c * XTS + c4 * 4) = o.u;
    }
    if (tid < 128) bsh[tid] = bias[tid];
    __syncthreads();

    // B-frag: lane holds in[tok = wave*16 + l15][c = cg*32 + quad*8 + j]
    v8bf xf[4];
    {
        const int tok = wave * 16 + l15;
        #pragma unroll
        for (int cg = 0; cg < 4; ++cg) {
            union { __bf16 h[8]; v8bf v; } u;
            #pragma unroll
            for (int jj = 0; jj < 8; ++jj)
                u.h[jj] = xt[(cg * 32 + quad * 8 + jj) * XTS + tok];
            xf[cg] = u.v;
        }
    }

    const float scale = (job == 0) ? 0.0883883476483184f : 1.0f;  // 1/sqrt(128)

    for (int dg = 0; dg < 8; ++dg) {
        v8bf wf[4];
        #pragma unroll
        for (int cg = 0; cg < 4; ++cg) {
            const float* wp = W + (size_t)(dg * 16 + l15) * 128 + cg * 32 + quad * 8;
            float4 a = *(const float4*)wp;
            float4 c2 = *(const float4*)(wp + 4);
            union { __bf16 h[8]; v8bf v; } u;
            u.h[0] = (__bf16)a.x;  u.h[1] = (__bf16)a.y;  u.h[2] = (__bf16)a.z;  u.h[3] = (__bf16)a.w;
            u.h[4] = (__bf16)c2.x; u.h[5] = (__bf16)c2.y; u.h[6] = (__bf16)c2.z; u.h[7] = (__bf16)c2.w;
            wf[cg] = u.v;
        }
        v4f acc;
        #pragma unroll
        for (int r = 0; r < 4; ++r) acc[r] = bsh[dg * 16 + quad * 4 + r];
        #pragma unroll
        for (int cg = 0; cg < 4; ++cg)
            acc = MFMA16(wf[cg], xf[cg], acc, 0, 0, 0);
        #pragma unroll
        for (int r = 0; r < 4; ++r) acc[r] *= scale;

        const int tok = t0 + wave * 16 + l15;   // token within batch
        if (job <= 1) {
            __bf16* Out = (job == 0) ? Qfr : Kfr;
            const int tiles = (job == 0) ? 128 : 32;
            const size_t ci = ((size_t)(b * tiles + (tok >> 5)) * 8 + dg) * 64
                              + (quad >> 1) * 32 + (tok & 31);
            union { __bf16 h[4]; uint2 u; } o4;
            #pragma unroll
            for (int r = 0; r < 4; ++r) o4.h[r] = (__bf16)acc[r];
            *(uint2*)((char*)Out + ci * 16 + (quad & 1) * 8) = o4.u;
        } else {
            #pragma unroll
            for (int r = 0; r < 4; ++r) {
                const int d = dg * 16 + quad * 4 + r;
                const size_t ci = (((size_t)(b * 32 + (tok >> 5)) * 4 + (d >> 5)) * 2
                                   + ((tok >> 4) & 1)) * 64
                                  + ((tok >> 3) & 1) * 32 + (d & 31);
                Vfr[ci * 8 + (tok & 7)] = (__bf16)acc[r];
            }
        }
    }
}

// ---------------- Kernel 2: 4-way wave-split-K flash attention ---------------
// 1024 blocks x 256 thr (4 waves, 4 blocks/CU -> 4 waves/SIMD). Wave w owns
// keys w*256..w*256+255 (8 chunks of 32). Static-max softmax (p = exp(s-8)):
// no max tree, no rescale, no in-loop cross-lane except the P transpose.
__global__ __launch_bounds__(256, 4) void attn(
    const float* __restrict__ x, const __bf16* __restrict__ Qfr,
    const __bf16* __restrict__ Kfr, const __bf16* __restrict__ Vfr,
    float* __restrict__ out)
{
    __shared__ float Oacc[128 * 32];   // 16 KB [ch][q]
    __shared__ float Lacc[8 * 32];     // per-(wave,h) partial row sums

    const int tid = threadIdx.x;
    const int wave = tid >> 6, lane = tid & 63, r31 = lane & 31, h = lane >> 5;
    const int b = blockIdx.x >> 7;
    const int qt = blockIdx.x & 127;

    const v8bf* Qc = (const v8bf*)Qfr + (size_t)(b * 128 + qt) * 8 * 64;
    const v8bf* Kc = (const v8bf*)Kfr + (size_t)(b * 32 + wave * 8) * 8 * 64;
    const v8bf* Vc = (const v8bf*)Vfr + (size_t)(b * 32 + wave * 8) * 8 * 64;

    v8bf qf[8];
    #pragma unroll
    for (int s = 0; s < 8; ++s) qf[s] = Qc[s * 64 + lane];

    v16f o[4];
    #pragma unroll
    for (int cg = 0; cg < 4; ++cg)
        #pragma unroll
        for (int r = 0; r < 16; ++r) o[cg][r] = 0.f;
    float l = 0.f;

    for (int j = 0; j < 8; ++j) {
        // ---- S = K_chunk . Q^T : D[key][q=r31] ----
        v8bf kf[8];
        #pragma unroll
        for (int s = 0; s < 8; ++s) kf[s] = Kc[(j * 8 + s) * 64 + lane];
        v16f S;
        #pragma unroll
        for (int r = 0; r < 16; ++r) S[r] = 0.f;
        #pragma unroll
        for (int s = 0; s < 8; ++s) S = MFMA32(kf[s], qf[s], S, 0, 0, 0);

        // ---- static-max softmax: p = exp(s - SMAX), defer row-sum ----
        float p[16];
        #pragma unroll
        for (int r = 0; r < 16; ++r) { p[r] = __expf(S[r] - SMAX); l += p[r]; }

        // ---- P: D-layout -> B-frag layout via shfl_xor(32) ----
        v8bf pfr[2];
        #pragma unroll
        for (int t = 0; t < 2; ++t) {
            const int e = t * 8;
            const unsigned a0 = pkbf(p[e + 0], p[e + 1]);
            const unsigned a1 = pkbf(p[e + 2], p[e + 3]);
            const unsigned b0 = pkbf(p[e + 4], p[e + 5]);
            const unsigned b1 = pkbf(p[e + 6], p[e + 7]);
            const unsigned s0 = h ? a0 : b0;
            const unsigned s1 = h ? a1 : b1;
            const unsigned r0 = __shfl_xor(s0, 32);
            const unsigned r1 = __shfl_xor(s1, 32);
            union { unsigned u[4]; v8bf v; } fr;
            fr.u[0] = h ? r0 : a0;
            fr.u[1] = h ? r1 : a1;
            fr.u[2] = h ? b0 : r0;
            fr.u[3] = h ? b1 : r1;
            pfr[t] = fr.v;
        }

        // ---- O^T += Vt . P : D[ch][q=r31] ----
        #pragma unroll
        for (int cg = 0; cg < 4; ++cg) {
            #pragma unroll
            for (int t = 0; t < 2; ++t) {
                v8bf vf = Vc[((j * 4 + cg) * 2 + t) * 64 + lane];
                o[cg] = MFMA32(vf, pfr[t], o[cg], 0, 0, 0);
            }
        }
    }

    // ---- 4-way split-K merge through LDS ----
    Lacc[(wave * 2 + h) * 32 + r31] = l;
    // owner wave writes its own cg == wave
    #pragma unroll
    for (int r = 0; r < 16; ++r) {
        const int ch = wave * 32 + (r & 3) + 8 * (r >> 2) + 4 * h;
        Oacc[ch * 32 + r31] = o[wave][r];
    }
    __syncthreads();
    #pragma unroll
    for (int cgo = 1; cgo < 4; ++cgo) {
        const int cg = (wave + cgo) & 3;
        #pragma unroll
        for (int r = 0; r < 16; ++r) {
            const int ch = cg * 32 + (r & 3) + 8 * (r >> 2) + 4 * h;
            atomicAdd(&Oacc[ch * 32 + r31], o[cg][r]);
        }
    }
    __syncthreads();

    float ls = 0.f;
    #pragma unroll
    for (int i = 0; i < 8; ++i) ls += Lacc[i * 32 + r31];
    const float linv = 1.0f / ls;

    // ---- epilogue: wave stores its owned 32 channels, residual added ----
    #pragma unroll
    for (int i = 0; i < 16; ++i) {
        const int ch = wave * 32 + i * 2 + h;
        const float val = Oacc[ch * 32 + r31] * linv;
        const size_t gi = (size_t)(b * 128 + ch) * NN + qt * 32 + r31;
        out[gi] = x[gi] + val;
    }
}

extern "C" void kernel_launch(void* const* d_in, const int* in_sizes, int n_in,
                              void* d_out, int out_size, void* d_ws, size_t ws_size,
                              hipStream_t stream) {
    const float* x  = (const float*)d_in[0];
    const float* y  = (const float*)d_in[1];
    const float* Wq = (const float*)d_in[2];
    const float* bq = (const float*)d_in[3];
    const float* Wk = (const float*)d_in[4];
    const float* bk = (const float*)d_in[5];
    const float* Wv = (const float*)d_in[6];
    const float* bv = (const float*)d_in[7];
    float* out = (float*)d_out;

    __bf16* Qfr = (__bf16*)d_ws;                        // 8 MB
    __bf16* Kfr = Qfr + (size_t)BB * NN * 128;          // 2 MB
    __bf16* Vfr = Kfr + (size_t)BB * MMK * 128;         // 2 MB

    proj<<<768, 256, 0, stream>>>(x, y, Wq, bq, Wk, bk, Wv, bv, Qfr, Kfr, Vfr);
    attn<<<BB * (NN / 32), 256, 0, stream>>>(x, Qfr, Kfr, Vfr, out);
}

// Round 6
// 148.169 us; speedup vs baseline: 1.4607x; 1.4607x over previous
//
#include <hip/hip_runtime.h>

#define BB 8
#define NN 4096
#define MMK 1024
#define SMAX 8.0f

typedef __bf16 v8bf __attribute__((ext_vector_type(8)));
typedef float v4f __attribute__((ext_vector_type(4)));
typedef float v16f __attribute__((ext_vector_type(16)));
#define MFMA16 __builtin_amdgcn_mfma_f32_16x16x32_bf16
#define MFMA32 __builtin_amdgcn_mfma_f32_32x32x16_bf16

static __device__ __forceinline__ unsigned pkbf(float a, float b) {
    union { __bf16 h[2]; unsigned u; } o;
    o.h[0] = (__bf16)a; o.h[1] = (__bf16)b;
    return o.u;
}

// ---------------- Kernel 1: projections via MFMA, OUTPUT IN FRAG ORDER -------
// 64-token tiles: Q blocks 0..511, K 512..639, V 640..767.
// Frag layouts (16B chunk per lane), tok within batch:
//  Qfr chunk = ((b*128 + qt)*8 + s)*64 + lane : Q[q=qt*32+r31][c=s*16+h*8+j]
//  Kfr chunk = ((b*32  + kt)*8 + s)*64 + lane : K[key=kt*32+r31][c=s*16+h*8+j]
//  Vfr chunk = (((b*32 + kt)*4 + cg)*2 + t)*64 + lane : Vt[ch=cg*32+r31][key=kt*32+t*16+h*8+j]
#define XTS 68
__global__ __launch_bounds__(256, 1) void proj(
    const float* __restrict__ x, const float* __restrict__ y,
    const float* __restrict__ Wq, const float* __restrict__ bq,
    const float* __restrict__ Wk, const float* __restrict__ bk,
    const float* __restrict__ Wv, const float* __restrict__ bv,
    __bf16* __restrict__ Qfr, __bf16* __restrict__ Kfr, __bf16* __restrict__ Vfr)
{
    __shared__ __align__(16) __bf16 xt[128 * XTS];
    __shared__ float bsh[128];

    const int tid = threadIdx.x;
    const int wave = tid >> 6, lane = tid & 63, l15 = lane & 15, quad = lane >> 4;
    const int bid = blockIdx.x;

    int job, b, t0, stride;
    const float *in, *W, *bias;
    if (bid < 512)      { job = 0; b = bid >> 6;         t0 = (bid & 63) * 64;         in = x; stride = NN;  W = Wq; bias = bq; }
    else if (bid < 640) { job = 1; b = (bid - 512) >> 4; t0 = ((bid - 512) & 15) * 64; in = y; stride = MMK; W = Wk; bias = bk; }
    else                { job = 2; b = (bid - 640) >> 4; t0 = ((bid - 640) & 15) * 64; in = y; stride = MMK; W = Wv; bias = bv; }

    #pragma unroll
    for (int i = 0; i < 8; ++i) {
        const int s = i * 256 + tid;
        const int c = s >> 4, c4 = s & 15;
        float4 v = *(const float4*)(in + (size_t)(b * 128 + c) * stride + t0 + c4 * 4);
        union { __bf16 h[4]; uint2 u; } o;
        o.h[0] = (__bf16)v.x; o.h[1] = (__bf16)v.y; o.h[2] = (__bf16)v.z; o.h[3] = (__bf16)v.w;
        *(uint2*)(xt + c * XTS + c4 * 4) = o.u;
    }
    if (tid < 128) bsh[tid] = bias[tid];
    __syncthreads();

    v8bf xf[4];
    {
        const int tok = wave * 16 + l15;
        #pragma unroll
        for (int cg = 0; cg < 4; ++cg) {
            union { __bf16 h[8]; v8bf v; } u;
            #pragma unroll
            for (int jj = 0; jj < 8; ++jj)
                u.h[jj] = xt[(cg * 32 + quad * 8 + jj) * XTS + tok];
            xf[cg] = u.v;
        }
    }

    const float scale = (job == 0) ? 0.0883883476483184f : 1.0f;  // 1/sqrt(128)

    for (int dg = 0; dg < 8; ++dg) {
        v8bf wf[4];
        #pragma unroll
        for (int cg = 0; cg < 4; ++cg) {
            const float* wp = W + (size_t)(dg * 16 + l15) * 128 + cg * 32 + quad * 8;
            float4 a = *(const float4*)wp;
            float4 c2 = *(const float4*)(wp + 4);
            union { __bf16 h[8]; v8bf v; } u;
            u.h[0] = (__bf16)a.x;  u.h[1] = (__bf16)a.y;  u.h[2] = (__bf16)a.z;  u.h[3] = (__bf16)a.w;
            u.h[4] = (__bf16)c2.x; u.h[5] = (__bf16)c2.y; u.h[6] = (__bf16)c2.z; u.h[7] = (__bf16)c2.w;
            wf[cg] = u.v;
        }
        v4f acc;
        #pragma unroll
        for (int r = 0; r < 4; ++r) acc[r] = bsh[dg * 16 + quad * 4 + r];
        #pragma unroll
        for (int cg = 0; cg < 4; ++cg)
            acc = MFMA16(wf[cg], xf[cg], acc, 0, 0, 0);
        #pragma unroll
        for (int r = 0; r < 4; ++r) acc[r] *= scale;

        const int tok = t0 + wave * 16 + l15;
        if (job <= 1) {
            __bf16* Out = (job == 0) ? Qfr : Kfr;
            const int tiles = (job == 0) ? 128 : 32;
            const size_t ci = ((size_t)(b * tiles + (tok >> 5)) * 8 + dg) * 64
                              + (quad >> 1) * 32 + (tok & 31);
            union { __bf16 h[4]; uint2 u; } o4;
            #pragma unroll
            for (int r = 0; r < 4; ++r) o4.h[r] = (__bf16)acc[r];
            *(uint2*)((char*)Out + ci * 16 + (quad & 1) * 8) = o4.u;
        } else {
            #pragma unroll
            for (int r = 0; r < 4; ++r) {
                const int d = dg * 16 + quad * 4 + r;
                const size_t ci = (((size_t)(b * 32 + (tok >> 5)) * 4 + (d >> 5)) * 2
                                   + ((tok >> 4) & 1)) * 64
                                  + ((tok >> 3) & 1) * 32 + (d & 31);
                Vfr[ci * 8 + (tok & 7)] = (__bf16)acc[r];
            }
        }
    }
}

// ---------------- Kernel 2: 2-wave split-K flash attn, prefetched, static-max
// 1024 blocks x 128 thr. Wave w owns keys w*512..w*512+511 (16 chunks of 32).
// All frag loads coalesced 1KB b128; next chunk's K AND V prefetched into
// registers before current chunk's compute (hides ~300cyc L2 latency).
__global__ __launch_bounds__(128, 2) void attn(
    const float* __restrict__ x, const __bf16* __restrict__ Qfr,
    const __bf16* __restrict__ Kfr, const __bf16* __restrict__ Vfr,
    float* __restrict__ out)
{
    __shared__ float Oacc[128 * 32];   // 16 KB [ch][q]
    __shared__ float Lacc[2][32];

    const int tid = threadIdx.x;
    const int wave = tid >> 6, lane = tid & 63, r31 = lane & 31, h = lane >> 5;
    const int b = blockIdx.x >> 7;
    const int qt = blockIdx.x & 127;

    const v8bf* Qc = (const v8bf*)Qfr + (size_t)(b * 128 + qt) * 8 * 64;
    const v8bf* Kc = (const v8bf*)Kfr + (size_t)(b * 32 + wave * 16) * 8 * 64;
    const v8bf* Vc = (const v8bf*)Vfr + (size_t)(b * 32 + wave * 16) * 8 * 64;

    v8bf qf[8];
    #pragma unroll
    for (int s = 0; s < 8; ++s) qf[s] = Qc[s * 64 + lane];

    v16f o[4];
    #pragma unroll
    for (int cg = 0; cg < 4; ++cg)
        #pragma unroll
        for (int r = 0; r < 16; ++r) o[cg][r] = 0.f;
    float l = 0.f;

    // preload chunk 0 fragments (K and V share the (j*8+s)*64 stride)
    v8bf kf[8], vf[8];
    #pragma unroll
    for (int s = 0; s < 8; ++s) kf[s] = Kc[s * 64 + lane];
    #pragma unroll
    for (int s = 0; s < 8; ++s) vf[s] = Vc[s * 64 + lane];

    #pragma unroll
    for (int j = 0; j < 16; ++j) {
        // ---- prefetch chunk j+1 (K and V) ----
        v8bf kn[8], vn[8];
        if (j < 15) {
            #pragma unroll
            for (int s = 0; s < 8; ++s) kn[s] = Kc[((j + 1) * 8 + s) * 64 + lane];
            #pragma unroll
            for (int s = 0; s < 8; ++s) vn[s] = Vc[((j + 1) * 8 + s) * 64 + lane];
        }

        // ---- S = K_chunk . Q^T : D[key][q=r31] ----
        v16f S;
        #pragma unroll
        for (int r = 0; r < 16; ++r) S[r] = 0.f;
        #pragma unroll
        for (int s = 0; s < 8; ++s) S = MFMA32(kf[s], qf[s], S, 0, 0, 0);

        // ---- static-max softmax: p = exp(s - SMAX), defer row-sum ----
        float p[16];
        #pragma unroll
        for (int r = 0; r < 16; ++r) { p[r] = __expf(S[r] - SMAX); l += p[r]; }

        // ---- P: D-layout -> B-frag layout via shfl_xor(32) ----
        v8bf pfr[2];
        #pragma unroll
        for (int t = 0; t < 2; ++t) {
            const int e = t * 8;
            const unsigned a0 = pkbf(p[e + 0], p[e + 1]);
            const unsigned a1 = pkbf(p[e + 2], p[e + 3]);
            const unsigned b0 = pkbf(p[e + 4], p[e + 5]);
            const unsigned b1 = pkbf(p[e + 6], p[e + 7]);
            const unsigned s0 = h ? a0 : b0;
            const unsigned s1 = h ? a1 : b1;
            const unsigned r0 = __shfl_xor(s0, 32);
            const unsigned r1 = __shfl_xor(s1, 32);
            union { unsigned u[4]; v8bf v; } fr;
            fr.u[0] = h ? r0 : a0;
            fr.u[1] = h ? r1 : a1;
            fr.u[2] = h ? b0 : r0;
            fr.u[3] = h ? b1 : r1;
            pfr[t] = fr.v;
        }

        // ---- O^T += Vt . P : D[ch][q=r31] ----
        #pragma unroll
        for (int cg = 0; cg < 4; ++cg)
            #pragma unroll
            for (int t = 0; t < 2; ++t)
                o[cg] = MFMA32(vf[cg * 2 + t], pfr[t], o[cg], 0, 0, 0);

        // rotate buffers (dissolves under full unroll)
        #pragma unroll
        for (int s = 0; s < 8; ++s) { kf[s] = kn[s]; vf[s] = vn[s]; }
    }

    // ---- split-K merge: partials add (no max exchange needed) ----
    l += __shfl_xor(l, 32);                // sum across h halves -> row sum
    if (h == 0) Lacc[wave][r31] = l;
    if (wave == 0) {
        #pragma unroll
        for (int cg = 0; cg < 4; ++cg)
            #pragma unroll
            for (int r = 0; r < 16; ++r) {
                const int ch = cg * 32 + (r & 3) + 8 * (r >> 2) + 4 * h;
                Oacc[ch * 32 + r31] = o[cg][r];
            }
    }
    __syncthreads();
    if (wave == 1) {
        #pragma unroll
        for (int cg = 0; cg < 4; ++cg)
            #pragma unroll
            for (int r = 0; r < 16; ++r) {
                const int ch = cg * 32 + (r & 3) + 8 * (r >> 2) + 4 * h;
                Oacc[ch * 32 + r31] += o[cg][r];
            }
    }
    __syncthreads();

    const float linv = 1.0f / (Lacc[0][r31] + Lacc[1][r31]);

    // ---- epilogue: out = x + O/l; each (wave,h) half-wave owns 32 channels --
    #pragma unroll
    for (int i = 0; i < 32; ++i) {
        const int ch = (wave * 2 + h) + i * 4;
        const float val = Oacc[ch * 32 + r31] * linv;
        const size_t gi = (size_t)(b * 128 + ch) * NN + qt * 32 + r31;
        out[gi] = x[gi] + val;
    }
}

extern "C" void kernel_launch(void* const* d_in, const int* in_sizes, int n_in,
                              void* d_out, int out_size, void* d_ws, size_t ws_size,
                              hipStream_t stream) {
    const float* x  = (const float*)d_in[0];
    const float* y  = (const float*)d_in[1];
    const float* Wq = (const float*)d_in[2];
    const float* bq = (const float*)d_in[3];
    const float* Wk = (const float*)d_in[4];
    const float* bk = (const float*)d_in[5];
    const float* Wv = (const float*)d_in[6];
    const float* bv = (const float*)d_in[7];
    float* out = (float*)d_out;

    __bf16* Qfr = (__bf16*)d_ws;                        // 8 MB
    __bf16* Kfr = Qfr + (size_t)BB * NN * 128;          // 2 MB
    __bf16* Vfr = Kfr + (size_t)BB * MMK * 128;         // 2 MB

    proj<<<768, 256, 0, stream>>>(x, y, Wq, bq, Wk, bk, Wv, bv, Qfr, Kfr, Vfr);
    attn<<<BB * (NN / 32), 128, 0, stream>>>(x, Qfr, Kfr, Vfr, out);
}

// Round 7
// 129.512 us; speedup vs baseline: 1.6711x; 1.1441x over previous
//
#include <hip/hip_runtime.h>

#define BB 8
#define NN 4096
#define MMK 1024
#define SMAX 2.0f
#define SCL 0.0883883476483184f   // 1/sqrt(128)

typedef __bf16 v8bf __attribute__((ext_vector_type(8)));
typedef float v4f __attribute__((ext_vector_type(4)));
typedef float v16f __attribute__((ext_vector_type(16)));
#define MFMA16 __builtin_amdgcn_mfma_f32_16x16x32_bf16
#define MFMA32F8 __builtin_amdgcn_mfma_f32_32x32x16_fp8_fp8

static __device__ __forceinline__ unsigned pk4(float a, float b, float c, float d) {
    int u = __builtin_amdgcn_cvt_pk_fp8_f32(a, b, 0, false);
    u = __builtin_amdgcn_cvt_pk_fp8_f32(c, d, u, true);
    return (unsigned)u;
}
static __device__ __forceinline__ long long mk64(unsigned lo, unsigned hi) {
    return (long long)(((unsigned long long)hi << 32) | lo);
}
static __device__ __forceinline__ long long lo64(uint4 u) { return mk64(u.x, u.y); }
static __device__ __forceinline__ long long hi64(uint4 u) { return mk64(u.z, u.w); }

// ---------------- Kernel 1: projections via bf16 MFMA, fp8 FRAG-ORDER output
// Byte layouts (1024B chunks of 64 lanes x 16B, lane = h*32 + r31):
//  Q[q][c]  -> chunk ((b*128+qt)*4 + (c>>5)), byte ((c>>3)&1)*512 + (q&31)*16 + ((c>>4)&1)*8 + (c&7)
//  K[k][c]  -> chunk ((b*32 +kt)*4 + (c>>5)), byte ((c>>3)&1)*512 + (k&31)*16 + ((c>>4)&1)*8 + (c&7)
//  Vt[ch][k]-> chunk ((b*32 +kt)*4 + (ch>>5)), byte ((k>>3)&1)*512 + (ch&31)*16 + ((k>>4)&1)*8 + (k&7)
#define XTS 68
__global__ __launch_bounds__(256, 1) void proj(
    const float* __restrict__ x, const float* __restrict__ y,
    const float* __restrict__ Wq, const float* __restrict__ bq,
    const float* __restrict__ Wk, const float* __restrict__ bk,
    const float* __restrict__ Wv, const float* __restrict__ bv,
    unsigned char* __restrict__ Qfr, unsigned char* __restrict__ Kfr,
    unsigned char* __restrict__ Vfr)
{
    __shared__ __align__(16) __bf16 xt[128 * XTS];
    __shared__ float bsh[128];

    const int tid = threadIdx.x;
    const int wave = tid >> 6, lane = tid & 63, l15 = lane & 15, quad = lane >> 4;
    const int bid = blockIdx.x;

    int job, b, t0, stride;
    const float *in, *W, *bias;
    if (bid < 512)      { job = 0; b = bid >> 6;         t0 = (bid & 63) * 64;         in = x; stride = NN;  W = Wq; bias = bq; }
    else if (bid < 640) { job = 1; b = (bid - 512) >> 4; t0 = ((bid - 512) & 15) * 64; in = y; stride = MMK; W = Wk; bias = bk; }
    else                { job = 2; b = (bid - 640) >> 4; t0 = ((bid - 640) & 15) * 64; in = y; stride = MMK; W = Wv; bias = bv; }

    #pragma unroll
    for (int i = 0; i < 8; ++i) {
        const int s = i * 256 + tid;
        const int c = s >> 4, c4 = s & 15;
        float4 v = *(const float4*)(in + (size_t)(b * 128 + c) * stride + t0 + c4 * 4);
        union { __bf16 h[4]; uint2 u; } o;
        o.h[0] = (__bf16)v.x; o.h[1] = (__bf16)v.y; o.h[2] = (__bf16)v.z; o.h[3] = (__bf16)v.w;
        *(uint2*)(xt + c * XTS + c4 * 4) = o.u;
    }
    if (tid < 128) bsh[tid] = bias[tid];
    __syncthreads();

    v8bf xf[4];
    {
        const int tok = wave * 16 + l15;
        #pragma unroll
        for (int cg = 0; cg < 4; ++cg) {
            union { __bf16 h[8]; v8bf v; } u;
            #pragma unroll
            for (int jj = 0; jj < 8; ++jj)
                u.h[jj] = xt[(cg * 32 + quad * 8 + jj) * XTS + tok];
            xf[cg] = u.v;
        }
    }

    for (int dg = 0; dg < 8; ++dg) {
        v8bf wf[4];
        #pragma unroll
        for (int cg = 0; cg < 4; ++cg) {
            const float* wp = W + (size_t)(dg * 16 + l15) * 128 + cg * 32 + quad * 8;
            float4 a = *(const float4*)wp;
            float4 c2 = *(const float4*)(wp + 4);
            union { __bf16 h[8]; v8bf v; } u;
            u.h[0] = (__bf16)a.x;  u.h[1] = (__bf16)a.y;  u.h[2] = (__bf16)a.z;  u.h[3] = (__bf16)a.w;
            u.h[4] = (__bf16)c2.x; u.h[5] = (__bf16)c2.y; u.h[6] = (__bf16)c2.z; u.h[7] = (__bf16)c2.w;
            wf[cg] = u.v;
        }
        v4f acc;
        #pragma unroll
        for (int r = 0; r < 4; ++r) acc[r] = bsh[dg * 16 + quad * 4 + r];
        #pragma unroll
        for (int cg = 0; cg < 4; ++cg)
            acc = MFMA16(wf[cg], xf[cg], acc, 0, 0, 0);

        const int tok = t0 + wave * 16 + l15;       // token within batch
        const int d0 = dg * 16 + quad * 4;          // first of 4 consecutive channels
        const unsigned u32 = pk4(acc[0], acc[1], acc[2], acc[3]);  // e4m3 RNE

        if (job <= 1) {
            unsigned char* Out = (job == 0) ? Qfr : Kfr;
            const int tiles = (job == 0) ? 128 : 32;
            const size_t off = ((size_t)(b * tiles + (tok >> 5)) * 4 + (d0 >> 5)) * 1024
                             + ((d0 >> 3) & 1) * 512 + (tok & 31) * 16
                             + ((d0 >> 4) & 1) * 8 + (d0 & 7);
            *(unsigned*)(Out + off) = u32;
        } else {
            #pragma unroll
            for (int r = 0; r < 4; ++r) {
                const int ch = d0 + r, key = tok;
                const size_t off = ((size_t)(b * 32 + (key >> 5)) * 4 + (ch >> 5)) * 1024
                                 + ((key >> 3) & 1) * 512 + (ch & 31) * 16
                                 + ((key >> 4) & 1) * 8 + (key & 7);
                Vfr[off] = (unsigned char)(u32 >> (8 * r));
            }
        }
    }
}

// ---------------- Kernel 2: fp8 2-wave split-K flash attn, register prefetch -
// 1024 blocks x 128 thr. Wave w owns keys w*512..+511 (16 chunks of 32).
// All frag loads coalesced 1KB b128; fp8 halves frag regs so the distance-1
// prefetch (kc/vc + kn/vn = 64 VGPRs) survives register allocation.
__global__ __launch_bounds__(128, 2) void attn(
    const float* __restrict__ x, const unsigned char* __restrict__ Qfr,
    const unsigned char* __restrict__ Kfr, const unsigned char* __restrict__ Vfr,
    float* __restrict__ out)
{
    __shared__ float Oacc[128 * 32];   // 16 KB [ch][q]
    __shared__ float Lacc[2][32];

    const int tid = threadIdx.x;
    const int wave = tid >> 6, lane = tid & 63, r31 = lane & 31, h = lane >> 5;
    const int b = blockIdx.x >> 7;
    const int qt = blockIdx.x & 127;

    const uint4* Qc = (const uint4*)Qfr + (size_t)(b * 128 + qt) * 4 * 64;
    const uint4* Kc = (const uint4*)Kfr + (size_t)(b * 32 + wave * 16) * 4 * 64;
    const uint4* Vc = (const uint4*)Vfr + (size_t)(b * 32 + wave * 16) * 4 * 64;

    uint4 qv[4];
    #pragma unroll
    for (int s2 = 0; s2 < 4; ++s2) qv[s2] = Qc[s2 * 64 + lane];

    v16f o[4];
    #pragma unroll
    for (int cg = 0; cg < 4; ++cg)
        #pragma unroll
        for (int r = 0; r < 16; ++r) o[cg][r] = 0.f;
    float l = 0.f;

    uint4 kc[4], vc[4];
    #pragma unroll
    for (int s2 = 0; s2 < 4; ++s2) kc[s2] = Kc[s2 * 64 + lane];
    #pragma unroll
    for (int s2 = 0; s2 < 4; ++s2) vc[s2] = Vc[s2 * 64 + lane];

    #pragma unroll
    for (int j = 0; j < 16; ++j) {
        // ---- prefetch chunk j+1 ----
        uint4 kn[4], vn[4];
        if (j < 15) {
            #pragma unroll
            for (int s2 = 0; s2 < 4; ++s2) kn[s2] = Kc[((j + 1) * 4 + s2) * 64 + lane];
            #pragma unroll
            for (int s2 = 0; s2 < 4; ++s2) vn[s2] = Vc[((j + 1) * 4 + s2) * 64 + lane];
        }

        // ---- S = K . Q^T (raw, unscaled): D[key][q=r31] ----
        v16f S;
        #pragma unroll
        for (int r = 0; r < 16; ++r) S[r] = 0.f;
        #pragma unroll
        for (int s2 = 0; s2 < 4; ++s2) {
            S = MFMA32F8(lo64(kc[s2]), lo64(qv[s2]), S, 0, 0, 0);
            S = MFMA32F8(hi64(kc[s2]), hi64(qv[s2]), S, 0, 0, 0);
        }

        // ---- static-max softmax: p = exp(S*scale - SMAX) ----
        float p[16];
        #pragma unroll
        for (int r = 0; r < 16; ++r) { p[r] = __expf(fmaf(S[r], SCL, -SMAX)); l += p[r]; }

        // ---- P -> fp8 B-frags: pack quads, one shfl per 16-key group ----
        // lane(h) owns keys: A={4h..4h+3}(p0-3) B={8+4h..}(p4-7) C={16+4h..}(p8-11) D={24+4h..}(p12-15)
        const unsigned qa = pk4(p[0], p[1], p[2], p[3]);
        const unsigned qb = pk4(p[4], p[5], p[6], p[7]);
        const unsigned qc = pk4(p[8], p[9], p[10], p[11]);
        const unsigned qd = pk4(p[12], p[13], p[14], p[15]);
        unsigned e0 = h ? qa : qb; e0 = __shfl_xor(e0, 32);
        unsigned e1 = h ? qc : qd; e1 = __shfl_xor(e1, 32);
        const long long pf0 = mk64(h ? e0 : qa, h ? qb : e0);   // keys (h?8:0)..+7
        const long long pf1 = mk64(h ? e1 : qc, h ? qd : e1);   // keys 16+(h?8:0)..+7

        // ---- O^T += Vt . P : D[ch][q=r31] ----
        #pragma unroll
        for (int cg = 0; cg < 4; ++cg) {
            o[cg] = MFMA32F8(lo64(vc[cg]), pf0, o[cg], 0, 0, 0);
            o[cg] = MFMA32F8(hi64(vc[cg]), pf1, o[cg], 0, 0, 0);
        }

        // rotate (dissolves under full unroll)
        #pragma unroll
        for (int s2 = 0; s2 < 4; ++s2) { kc[s2] = kn[s2]; vc[s2] = vn[s2]; }
    }

    // ---- split-K merge: pure adds (shared static max) ----
    l += __shfl_xor(l, 32);
    if (h == 0) Lacc[wave][r31] = l;
    if (wave == 0) {
        #pragma unroll
        for (int cg = 0; cg < 4; ++cg)
            #pragma unroll
            for (int r = 0; r < 16; ++r) {
                const int ch = cg * 32 + (r & 3) + 8 * (r >> 2) + 4 * h;
                Oacc[ch * 32 + r31] = o[cg][r];
            }
    }
    __syncthreads();
    if (wave == 1) {
        #pragma unroll
        for (int cg = 0; cg < 4; ++cg)
            #pragma unroll
            for (int r = 0; r < 16; ++r) {
                const int ch = cg * 32 + (r & 3) + 8 * (r >> 2) + 4 * h;
                Oacc[ch * 32 + r31] += o[cg][r];
            }
    }
    __syncthreads();

    const float linv = 1.0f / (Lacc[0][r31] + Lacc[1][r31]);

    // ---- epilogue: out = x + O/l; each (wave,h) half-wave owns 32 channels --
    #pragma unroll
    for (int i = 0; i < 32; ++i) {
        const int ch = (wave * 2 + h) + i * 4;
        const float val = Oacc[ch * 32 + r31] * linv;
        const size_t gi = (size_t)(b * 128 + ch) * NN + qt * 32 + r31;
        out[gi] = x[gi] + val;
    }
}

extern "C" void kernel_launch(void* const* d_in, const int* in_sizes, int n_in,
                              void* d_out, int out_size, void* d_ws, size_t ws_size,
                              hipStream_t stream) {
    const float* x  = (const float*)d_in[0];
    const float* y  = (const float*)d_in[1];
    const float* Wq = (const float*)d_in[2];
    const float* bq = (const float*)d_in[3];
    const float* Wk = (const float*)d_in[4];
    const float* bk = (const float*)d_in[5];
    const float* Wv = (const float*)d_in[6];
    const float* bv = (const float*)d_in[7];
    float* out = (float*)d_out;

    unsigned char* Qfr = (unsigned char*)d_ws;          // 4 MB
    unsigned char* Kfr = Qfr + (size_t)BB * NN * 128;   // 1 MB
    unsigned char* Vfr = Kfr + (size_t)BB * MMK * 128;  // 1 MB

    proj<<<768, 256, 0, stream>>>(x, y, Wq, bq, Wk, bk, Wv, bv, Qfr, Kfr, Vfr);
    attn<<<BB * (NN / 32), 128, 0, stream>>>(x, Qfr, Kfr, Vfr, out);
}

// Round 8
// 125.108 us; speedup vs baseline: 1.7299x; 1.0352x over previous
//
#include <hip/hip_runtime.h>

#define BB 8
#define NN 4096
#define MMK 1024
#define SMAX 2.0f
#define SCL 0.0883883476483184f   // 1/sqrt(128)

typedef __bf16 v8bf __attribute__((ext_vector_type(8)));
typedef float v4f __attribute__((ext_vector_type(4)));
typedef float v16f __attribute__((ext_vector_type(16)));
#define MFMA16 __builtin_amdgcn_mfma_f32_16x16x32_bf16
#define MFMA32F8 __builtin_amdgcn_mfma_f32_32x32x16_fp8_fp8

static __device__ __forceinline__ unsigned pk4(float a, float b, float c, float d) {
    int u = __builtin_amdgcn_cvt_pk_fp8_f32(a, b, 0, false);
    u = __builtin_amdgcn_cvt_pk_fp8_f32(c, d, u, true);
    return (unsigned)u;
}
static __device__ __forceinline__ long long mk64(unsigned lo, unsigned hi) {
    return (long long)(((unsigned long long)hi << 32) | lo);
}
static __device__ __forceinline__ long long lo64(uint4 u) { return mk64(u.x, u.y); }
static __device__ __forceinline__ long long hi64(uint4 u) { return mk64(u.z, u.w); }

// split-chain S computation: two independent 4-deep MFMA chains
#define COMPUTE_S(DST, KB)                                                  \
    do {                                                                    \
        v16f a1, a2;                                                        \
        _Pragma("unroll")                                                   \
        for (int r_ = 0; r_ < 16; ++r_) { a1[r_] = 0.f; a2[r_] = 0.f; }     \
        a1 = MFMA32F8(lo64(KB[0]), lo64(qv[0]), a1, 0, 0, 0);               \
        a2 = MFMA32F8(lo64(KB[2]), lo64(qv[2]), a2, 0, 0, 0);               \
        a1 = MFMA32F8(hi64(KB[0]), hi64(qv[0]), a1, 0, 0, 0);               \
        a2 = MFMA32F8(hi64(KB[2]), hi64(qv[2]), a2, 0, 0, 0);               \
        a1 = MFMA32F8(lo64(KB[1]), lo64(qv[1]), a1, 0, 0, 0);               \
        a2 = MFMA32F8(lo64(KB[3]), lo64(qv[3]), a2, 0, 0, 0);               \
        a1 = MFMA32F8(hi64(KB[1]), hi64(qv[1]), a1, 0, 0, 0);               \
        a2 = MFMA32F8(hi64(KB[3]), hi64(qv[3]), a2, 0, 0, 0);               \
        _Pragma("unroll")                                                   \
        for (int r_ = 0; r_ < 16; ++r_) DST[r_] = a1[r_] + a2[r_];          \
    } while (0)

// ---------------- Kernel 1: projections via bf16 MFMA, fp8 FRAG-ORDER output
// Byte layouts (1024B chunks of 64 lanes x 16B, lane = h*32 + r31):
//  Q[q][c]  -> chunk ((b*128+qt)*4 + (c>>5)), byte ((c>>3)&1)*512 + (q&31)*16 + ((c>>4)&1)*8 + (c&7)
//  K[k][c]  -> chunk ((b*32 +kt)*4 + (c>>5)), byte ((c>>3)&1)*512 + (k&31)*16 + ((c>>4)&1)*8 + (c&7)
//  Vt[ch][k]-> chunk ((b*32 +kt)*4 + (ch>>5)), byte ((k>>3)&1)*512 + (ch&31)*16 + ((k>>4)&1)*8 + (k&7)
#define XTS 68
__global__ __launch_bounds__(256, 1) void proj(
    const float* __restrict__ x, const float* __restrict__ y,
    const float* __restrict__ Wq, const float* __restrict__ bq,
    const float* __restrict__ Wk, const float* __restrict__ bk,
    const float* __restrict__ Wv, const float* __restrict__ bv,
    unsigned char* __restrict__ Qfr, unsigned char* __restrict__ Kfr,
    unsigned char* __restrict__ Vfr)
{
    __shared__ __align__(16) __bf16 xt[128 * XTS];
    __shared__ float bsh[128];

    const int tid = threadIdx.x;
    const int wave = tid >> 6, lane = tid & 63, l15 = lane & 15, quad = lane >> 4;
    const int bid = blockIdx.x;

    int job, b, t0, stride;
    const float *in, *W, *bias;
    if (bid < 512)      { job = 0; b = bid >> 6;         t0 = (bid & 63) * 64;         in = x; stride = NN;  W = Wq; bias = bq; }
    else if (bid < 640) { job = 1; b = (bid - 512) >> 4; t0 = ((bid - 512) & 15) * 64; in = y; stride = MMK; W = Wk; bias = bk; }
    else                { job = 2; b = (bid - 640) >> 4; t0 = ((bid - 640) & 15) * 64; in = y; stride = MMK; W = Wv; bias = bv; }

    #pragma unroll
    for (int i = 0; i < 8; ++i) {
        const int s = i * 256 + tid;
        const int c = s >> 4, c4 = s & 15;
        float4 v = *(const float4*)(in + (size_t)(b * 128 + c) * stride + t0 + c4 * 4);
        union { __bf16 h[4]; uint2 u; } o;
        o.h[0] = (__bf16)v.x; o.h[1] = (__bf16)v.y; o.h[2] = (__bf16)v.z; o.h[3] = (__bf16)v.w;
        *(uint2*)(xt + c * XTS + c4 * 4) = o.u;
    }
    if (tid < 128) bsh[tid] = bias[tid];
    __syncthreads();

    v8bf xf[4];
    {
        const int tok = wave * 16 + l15;
        #pragma unroll
        for (int cg = 0; cg < 4; ++cg) {
            union { __bf16 h[8]; v8bf v; } u;
            #pragma unroll
            for (int jj = 0; jj < 8; ++jj)
                u.h[jj] = xt[(cg * 32 + quad * 8 + jj) * XTS + tok];
            xf[cg] = u.v;
        }
    }

    for (int dg = 0; dg < 8; ++dg) {
        v8bf wf[4];
        #pragma unroll
        for (int cg = 0; cg < 4; ++cg) {
            const float* wp = W + (size_t)(dg * 16 + l15) * 128 + cg * 32 + quad * 8;
            float4 a = *(const float4*)wp;
            float4 c2 = *(const float4*)(wp + 4);
            union { __bf16 h[8]; v8bf v; } u;
            u.h[0] = (__bf16)a.x;  u.h[1] = (__bf16)a.y;  u.h[2] = (__bf16)a.z;  u.h[3] = (__bf16)a.w;
            u.h[4] = (__bf16)c2.x; u.h[5] = (__bf16)c2.y; u.h[6] = (__bf16)c2.z; u.h[7] = (__bf16)c2.w;
            wf[cg] = u.v;
        }
        v4f acc;
        #pragma unroll
        for (int r = 0; r < 4; ++r) acc[r] = bsh[dg * 16 + quad * 4 + r];
        #pragma unroll
        for (int cg = 0; cg < 4; ++cg)
            acc = MFMA16(wf[cg], xf[cg], acc, 0, 0, 0);

        const int tok = t0 + wave * 16 + l15;       // token within batch
        const int d0 = dg * 16 + quad * 4;          // first of 4 consecutive channels
        const unsigned u32 = pk4(acc[0], acc[1], acc[2], acc[3]);  // e4m3 RNE

        if (job <= 1) {
            unsigned char* Out = (job == 0) ? Qfr : Kfr;
            const int tiles = (job == 0) ? 128 : 32;
            const size_t off = ((size_t)(b * tiles + (tok >> 5)) * 4 + (d0 >> 5)) * 1024
                             + ((d0 >> 3) & 1) * 512 + (tok & 31) * 16
                             + ((d0 >> 4) & 1) * 8 + (d0 & 7);
            *(unsigned*)(Out + off) = u32;
        } else {
            #pragma unroll
            for (int r = 0; r < 4; ++r) {
                const int ch = d0 + r, key = tok;
                const size_t off = ((size_t)(b * 32 + (key >> 5)) * 4 + (ch >> 5)) * 1024
                                 + ((key >> 3) & 1) * 512 + (ch & 31) * 16
                                 + ((key >> 4) & 1) * 8 + (key & 7);
                Vfr[off] = (unsigned char)(u32 >> (8 * r));
            }
        }
    }
}

// ---------------- Kernel 2: fp8 split-K flash attn, software-pipelined -------
// 1024 blocks x 128 thr (2 waves, split-K=2). Pipeline: S(j+1) overlaps PV(j);
// K prefetched distance-2 at iter start, V at iter end (after its consumer).
__global__ __launch_bounds__(128, 2) void attn(
    const float* __restrict__ x, const unsigned char* __restrict__ Qfr,
    const unsigned char* __restrict__ Kfr, const unsigned char* __restrict__ Vfr,
    float* __restrict__ out)
{
    __shared__ float Oacc[128 * 32];   // 16 KB [ch][q]
    __shared__ float Lacc[2][32];

    const int tid = threadIdx.x;
    const int wave = tid >> 6, lane = tid & 63, r31 = lane & 31, h = lane >> 5;
    const int b = blockIdx.x >> 7;
    const int qt = blockIdx.x & 127;

    const uint4* Qc = (const uint4*)Qfr + (size_t)(b * 128 + qt) * 4 * 64;
    const uint4* Kc = (const uint4*)Kfr + (size_t)(b * 32 + wave * 16) * 4 * 64;
    const uint4* Vc = (const uint4*)Vfr + (size_t)(b * 32 + wave * 16) * 4 * 64;

    uint4 qv[4];
    #pragma unroll
    for (int s2 = 0; s2 < 4; ++s2) qv[s2] = Qc[s2 * 64 + lane];

    v16f o[4];
    #pragma unroll
    for (int cg = 0; cg < 4; ++cg)
        #pragma unroll
        for (int r = 0; r < 16; ++r) o[cg][r] = 0.f;
    float l0 = 0.f, l1 = 0.f, l2 = 0.f, l3 = 0.f;

    // preload chunks 0 and 1 (double buffer)
    uint4 kb[2][4], vb[2][4];
    #pragma unroll
    for (int s2 = 0; s2 < 4; ++s2) kb[0][s2] = Kc[s2 * 64 + lane];
    #pragma unroll
    for (int s2 = 0; s2 < 4; ++s2) vb[0][s2] = Vc[s2 * 64 + lane];
    #pragma unroll
    for (int s2 = 0; s2 < 4; ++s2) kb[1][s2] = Kc[(4 + s2) * 64 + lane];
    #pragma unroll
    for (int s2 = 0; s2 < 4; ++s2) vb[1][s2] = Vc[(4 + s2) * 64 + lane];

    v16f S;
    COMPUTE_S(S, kb[0]);               // S(0) in the preheader

    #pragma unroll
    for (int j = 0; j < 16; ++j) {
        const int cur = j & 1, nxt = (j + 1) & 1;

        // 1. prefetch K(j+2) into kb[cur] (its old K already consumed by S(j))
        if (j < 14) {
            #pragma unroll
            for (int s2 = 0; s2 < 4; ++s2)
                kb[cur][s2] = Kc[((j + 2) * 4 + s2) * 64 + lane];
        }

        // 2. softmax on S(j): p = exp(S*scale - SMAX), 4 partial row-sums
        float p[16];
        #pragma unroll
        for (int r = 0; r < 16; ++r) p[r] = __expf(fmaf(S[r], SCL, -SMAX));
        #pragma unroll
        for (int r = 0; r < 4; ++r) {
            l0 += p[r]; l1 += p[4 + r]; l2 += p[8 + r]; l3 += p[12 + r];
        }

        // P -> fp8 B-frags (one shfl per 16-key group)
        const unsigned qa = pk4(p[0], p[1], p[2], p[3]);
        const unsigned qb = pk4(p[4], p[5], p[6], p[7]);
        const unsigned qc = pk4(p[8], p[9], p[10], p[11]);
        const unsigned qd = pk4(p[12], p[13], p[14], p[15]);
        unsigned e0 = h ? qa : qb; e0 = __shfl_xor(e0, 32);
        unsigned e1 = h ? qc : qd; e1 = __shfl_xor(e1, 32);
        const long long pf0 = mk64(h ? e0 : qa, h ? qb : e0);
        const long long pf1 = mk64(h ? e1 : qc, h ? qd : e1);

        // 3. S(j+1) — independent of PV(j); scheduler interleaves both
        v16f Sn = S;
        if (j < 15) COMPUTE_S(Sn, kb[nxt]);

        // 4. PV(j) using vb[cur]
        #pragma unroll
        for (int cg = 0; cg < 4; ++cg) {
            o[cg] = MFMA32F8(lo64(vb[cur][cg]), pf0, o[cg], 0, 0, 0);
            o[cg] = MFMA32F8(hi64(vb[cur][cg]), pf1, o[cg], 0, 0, 0);
        }

        // 5. prefetch V(j+2) into vb[cur] (after PV(j) consumed it)
        if (j < 14) {
            #pragma unroll
            for (int s2 = 0; s2 < 4; ++s2)
                vb[cur][s2] = Vc[((j + 2) * 4 + s2) * 64 + lane];
        }

        S = Sn;
    }

    // ---- split-K merge: pure adds (shared static max) ----
    float l = (l0 + l1) + (l2 + l3);
    l += __shfl_xor(l, 32);
    if (h == 0) Lacc[wave][r31] = l;
    if (wave == 0) {
        #pragma unroll
        for (int cg = 0; cg < 4; ++cg)
            #pragma unroll
            for (int r = 0; r < 16; ++r) {
                const int ch = cg * 32 + (r & 3) + 8 * (r >> 2) + 4 * h;
                Oacc[ch * 32 + r31] = o[cg][r];
            }
    }
    __syncthreads();
    if (wave == 1) {
        #pragma unroll
        for (int cg = 0; cg < 4; ++cg)
            #pragma unroll
            for (int r = 0; r < 16; ++r) {
                const int ch = cg * 32 + (r & 3) + 8 * (r >> 2) + 4 * h;
                Oacc[ch * 32 + r31] += o[cg][r];
            }
    }
    __syncthreads();

    const float linv = 1.0f / (Lacc[0][r31] + Lacc[1][r31]);

    // ---- epilogue: out = x + O/l; each (wave,h) half-wave owns 32 channels --
    #pragma unroll
    for (int i = 0; i < 32; ++i) {
        const int ch = (wave * 2 + h) + i * 4;
        const float val = Oacc[ch * 32 + r31] * linv;
        const size_t gi = (size_t)(b * 128 + ch) * NN + qt * 32 + r31;
        out[gi] = x[gi] + val;
    }
}

extern "C" void kernel_launch(void* const* d_in, const int* in_sizes, int n_in,
                              void* d_out, int out_size, void* d_ws, size_t ws_size,
                              hipStream_t stream) {
    const float* x  = (const float*)d_in[0];
    const float* y  = (const float*)d_in[1];
    const float* Wq = (const float*)d_in[2];
    const float* bq = (const float*)d_in[3];
    const float* Wk = (const float*)d_in[4];
    const float* bk = (const float*)d_in[5];
    const float* Wv = (const float*)d_in[6];
    const float* bv = (const float*)d_in[7];
    float* out = (float*)d_out;

    unsigned char* Qfr = (unsigned char*)d_ws;          // 4 MB
    unsigned char* Kfr = Qfr + (size_t)BB * NN * 128;   // 1 MB
    unsigned char* Vfr = Kfr + (size_t)BB * MMK * 128;  // 1 MB

    proj<<<768, 256, 0, stream>>>(x, y, Wq, bq, Wk, bk, Wv, bv, Qfr, Kfr, Vfr);
    attn<<<BB * (NN / 32), 128, 0, stream>>>(x, Qfr, Kfr, Vfr, out);
}